// Round 2
// baseline (195.918 us; speedup 1.0000x reference)
//
#include <hip/hip_runtime.h>
#include <hip/hip_bf16.h>
#include <math.h>

// fp32 I/O confirmed. index_sample is int32.
// R9: no mega-atomic fan-in (WRITE_SIZE blowup, XCD coherence serialization).
// R10: shift-free softmax => disjoint non-atomic partials. Oc/Lc + finalize.
// R11: k_attn T14 async-STAGE + LDS dbuf (2 barriers/subtile); k_cumsum
// 2048-block two-level scan. 196->194us.
// R12 POST-MORTEM (R11 profile): k_measure 46us = latency-bound gather
// (VGPR=32 => zero MLP, 10 serial K-row round-trips). k_attn WRITE_SIZE
// 66MB vs 2.6MB expected = kreg[64] scratch spill (~126 floats/thread
// matches); VALUBusy 21%. SQ_LDS_BANK_CONFLICT=0 => LDS layout fine, no
// swizzle needed.
// R12: (a) k_measure: load all 10 idx + issue all 10 K float4 gathers
// up-front (MLP=10), then math. (b) k_attn: drop kreg[64]; QK reads sK
// float4 directly (20 FMA per chunk) => no spills.

#define BB 4
#define LL 2048
#define HH 8
#define DD 64
#define SS 40
#define UU 40
#define CC 64
#define LC (LL/CC)    // 32 (cumsum chunking)

#define KC    64      // staged k-tile rows
#define NCH2  8       // k-chunks (256 rows each)
#define UG    2       // u-groups of 20
#define KSUB  4       // 64-row subtiles per chunk
#define KPAD  68      // K/V LDS row stride (floats)
#define PPAD  68

// ---------------------------------------------------------------------------
// K1: sparsity measure M[bh*L + i] = max_s(Q_i . K_idx[i,s]) - sum_s(...)/L
// one wave per query. lane = (sg = lane>>4, d4 = lane&15).
// R12: all 10 sample gathers issued before any math (MLP).
// ---------------------------------------------------------------------------
__global__ void k_measure(const float* __restrict__ Q, const float* __restrict__ K,
                          const int* __restrict__ idx, float* __restrict__ M)
{
    int tid  = threadIdx.x;
    int lane = tid & 63;
    int wave = tid >> 6;
    int qid  = blockIdx.x * 4 + wave;          // qid = bh*L + i
    int bh = qid / LL;  int i = qid - bh * LL;
    int b  = bh / HH;   int h = bh - b * HH;

    int sg = lane >> 4;                        // sample group 0..3
    int d4 = lane & 15;                        // float4 slice of d

    const float* qrow = Q + (((size_t)b * LL + i) * HH + h) * DD;
    float4 qv = *(const float4*)(qrow + d4 * 4);

    const float* Kh = K + ((size_t)b * LL * HH + h) * DD;   // + kk*HH*DD
    const int* ip = idx + (size_t)i * SS;

    // issue ALL index loads, then ALL K-row gathers (10 in flight)
    int kk[10];
    #pragma unroll
    for (int u = 0; u < 10; ++u) kk[u] = ip[u * 4 + sg];
    float4 kv[10];
    #pragma unroll
    for (int u = 0; u < 10; ++u)
        kv[u] = *(const float4*)(Kh + (size_t)kk[u] * (HH * DD) + d4 * 4);

    float maxv = -INFINITY, sumv = 0.f;
    #pragma unroll
    for (int u = 0; u < 10; ++u) {
        float p = qv.x * kv[u].x;
        p = fmaf(qv.y, kv[u].y, p);
        p = fmaf(qv.z, kv[u].z, p);
        p = fmaf(qv.w, kv[u].w, p);
        p += __shfl_xor(p, 1);
        p += __shfl_xor(p, 2);
        p += __shfl_xor(p, 4);
        p += __shfl_xor(p, 8);
        maxv = fmaxf(maxv, p);
        sumv += p;
    }
    maxv = fmaxf(maxv, __shfl_xor(maxv, 16));
    sumv += __shfl_xor(sumv, 16);
    maxv = fmaxf(maxv, __shfl_xor(maxv, 32));
    sumv += __shfl_xor(sumv, 32);

    if (lane == 0) M[qid] = maxv - sumv * (1.0f / (float)LL);
}

// ---------------------------------------------------------------------------
// K2: top-40 per (b,h). One WAVE per bh, 2048 orderable keys in registers.
// Binary search for rank-40 threshold + idx tiebreak; zero LDS/barriers.
// ---------------------------------------------------------------------------
__global__ void k_topk(const float* __restrict__ M, int* __restrict__ topIdx)
{
    int lane = threadIdx.x;      // 64
    int bh   = blockIdx.x;
    const float* Mp = M + (size_t)bh * LL;

    unsigned k[32];
    #pragma unroll
    for (int r = 0; r < 32; ++r) {
        unsigned u = __float_as_uint(Mp[r * 64 + lane]);
        k[r] = (u & 0x80000000u) ? ~u : (u | 0x80000000u);  // order-preserving
    }

    unsigned T = 0u;
    for (int bit = 31; bit >= 0; --bit) {
        unsigned cand = T | (1u << bit);
        int c = 0;
        #pragma unroll
        for (int r = 0; r < 32; ++r) c += (k[r] >= cand) ? 1 : 0;
        #pragma unroll
        for (int off = 1; off < 64; off <<= 1) c += __shfl_xor(c, off);
        if (c >= UU) T = cand;
    }

    int cGT = 0, cGE = 0;
    #pragma unroll
    for (int r = 0; r < 32; ++r) {
        cGT += (k[r] > T) ? 1 : 0;
        cGE += (k[r] >= T) ? 1 : 0;
    }
    #pragma unroll
    for (int off = 1; off < 64; off <<= 1) {
        cGT += __shfl_xor(cGT, off);
        cGE += __shfl_xor(cGE, off);
    }

    int need = UU - cGT;
    int X = LL;
    if (cGE - cGT != need) {
        int lo2 = 0;
        for (int bit = 10; bit >= 0; --bit) {
            int cand = lo2 | (1 << bit);
            int c = 0;
            #pragma unroll
            for (int r = 0; r < 32; ++r)
                c += (k[r] == T && (r * 64 + lane) < cand) ? 1 : 0;
            #pragma unroll
            for (int off = 1; off < 64; off <<= 1) c += __shfl_xor(c, off);
            if (c < need) lo2 = cand;
        }
        X = lo2 + 1;
    }

    unsigned inMask = 0u;
    int cnt = 0;
    #pragma unroll
    for (int r = 0; r < 32; ++r) {
        bool in = (k[r] > T) || (k[r] == T && (r * 64 + lane) < X);
        if (in) { inMask |= 1u << r; ++cnt; }
    }
    int pre = cnt;
    #pragma unroll
    for (int off = 1; off < 64; off <<= 1) {
        int v = __shfl_up(pre, off);
        if (lane >= off) pre += v;
    }
    int slot = pre - cnt;
    #pragma unroll
    for (int r = 0; r < 32; ++r) {
        if ((inMask >> r) & 1u) {
            topIdx[bh * UU + slot] = r * 64 + lane;
            ++slot;
        }
    }
}

// ---------------------------------------------------------------------------
// K3: attention partials, shift-free softmax, NON-ATOMIC disjoint writes.
// Grid = bh(32) x ch(8) x ug(2) = 512 blocks, 256 threads, 2/CU resident.
// Double-buffered LDS + async-STAGE split (T14). Per subtile:
//   issue global loads (next subtile) -> QK (reads sK[cur] directly, 20 FMA
//   per float4 chunk; no kreg spill) -> barrier -> commit staged regs to
//   buf^1 -> PV -> barrier.
// ---------------------------------------------------------------------------
__launch_bounds__(256, 2)
__global__ void k_attn(const float* __restrict__ Q, const float* __restrict__ K,
                       const float* __restrict__ V, const int* __restrict__ topIdx,
                       float* __restrict__ Oc, float* __restrict__ Lc)
{
    __shared__ float sK[2][KC][KPAD];
    __shared__ float sV[2][KC][KPAD];
    __shared__ float sP[20][PPAD];
    __shared__ int   sPos[UU];

    int t   = threadIdx.x;
    int bid = blockIdx.x;
    int bh  = bid / (NCH2 * UG);
    int rem = bid % (NCH2 * UG);
    int ch  = rem / UG, ug = rem % UG;
    int b   = bh / HH, h = bh % HH;

    if (t < UU) sPos[t] = topIdx[bh * UU + t];

    int j  = t & 63;                 // QK lane -> k-row within subtile
    int w  = t >> 6, lane = t & 63;  // wave mapping
    int ub = __builtin_amdgcn_readfirstlane(w) * 5;   // local u base (0,5,10,15)

    // PV accumulators: thread = (d4p = t&15, tg = t>>4); local u = tg, 16+tg
    int d4p = t & 15, tg = t >> 4;
    float4 a0 = {0,0,0,0}, a1 = {0,0,0,0};
    float den[5] = {0.f, 0.f, 0.f, 0.f, 0.f};

    const float* Kh = K + ((size_t)b * LL * HH + h) * DD;
    const float* Vh = V + ((size_t)b * LL * HH + h) * DD;

    // staged-register tile: lane covers rows (it*16 + tg), float4 slice d4p
    float4 pk[4], pv[4];
    auto issue = [&](int k0) {
        #pragma unroll
        for (int it = 0; it < 4; ++it) {
            int r = it * 16 + tg;
            size_t go = (size_t)(k0 + r) * (HH * DD) + d4p * 4;
            pk[it] = *(const float4*)(Kh + go);
            pv[it] = *(const float4*)(Vh + go);
        }
    };
    auto commit = [&](int buf) {
        #pragma unroll
        for (int it = 0; it < 4; ++it) {
            int r = it * 16 + tg;
            *(float4*)&sK[buf][r][d4p * 4] = pk[it];
            *(float4*)&sV[buf][r][d4p * 4] = pv[it];
        }
    };

    int k0base = ch * KSUB * KC;
    issue(k0base);
    commit(0);
    __syncthreads();   // buf0 + sPos ready

    #pragma unroll
    for (int sub = 0; sub < KSUB; ++sub) {
        int cur = sub & 1;
        int k0  = k0base + sub * KC;

        if (sub + 1 < KSUB) issue(k0 + KC);   // async: in flight across QK

        // ---- QK: lane owns k-row j; Q rows via scalar (wave-uniform) loads ----
        int jg = k0 + j;
        {
            int p0 = __builtin_amdgcn_readfirstlane(sPos[ug * 20 + ub + 0]);
            int p1 = __builtin_amdgcn_readfirstlane(sPos[ug * 20 + ub + 1]);
            int p2 = __builtin_amdgcn_readfirstlane(sPos[ug * 20 + ub + 2]);
            int p3 = __builtin_amdgcn_readfirstlane(sPos[ug * 20 + ub + 3]);
            int p4 = __builtin_amdgcn_readfirstlane(sPos[ug * 20 + ub + 4]);
            const float* q0 = Q + (((size_t)b * LL + p0) * HH + h) * DD;
            const float* q1 = Q + (((size_t)b * LL + p1) * HH + h) * DD;
            const float* q2 = Q + (((size_t)b * LL + p2) * HH + h) * DD;
            const float* q3 = Q + (((size_t)b * LL + p3) * HH + h) * DD;
            const float* q4 = Q + (((size_t)b * LL + p4) * HH + h) * DD;
            float c0 = 0.f, c1 = 0.f, c2 = 0.f, c3 = 0.f, c4 = 0.f;
            #pragma unroll
            for (int d4 = 0; d4 < 16; ++d4) {
                float4 kk = *(const float4*)&sK[cur][j][d4 * 4];
                int d = d4 * 4;
                c0 = fmaf(kk.x, q0[d], c0); c0 = fmaf(kk.y, q0[d+1], c0);
                c0 = fmaf(kk.z, q0[d+2], c0); c0 = fmaf(kk.w, q0[d+3], c0);
                c1 = fmaf(kk.x, q1[d], c1); c1 = fmaf(kk.y, q1[d+1], c1);
                c1 = fmaf(kk.z, q1[d+2], c1); c1 = fmaf(kk.w, q1[d+3], c1);
                c2 = fmaf(kk.x, q2[d], c2); c2 = fmaf(kk.y, q2[d+1], c2);
                c2 = fmaf(kk.z, q2[d+2], c2); c2 = fmaf(kk.w, q2[d+3], c2);
                c3 = fmaf(kk.x, q3[d], c3); c3 = fmaf(kk.y, q3[d+1], c3);
                c3 = fmaf(kk.z, q3[d+2], c3); c3 = fmaf(kk.w, q3[d+3], c3);
                c4 = fmaf(kk.x, q4[d], c4); c4 = fmaf(kk.y, q4[d+1], c4);
                c4 = fmaf(kk.z, q4[d+2], c4); c4 = fmaf(kk.w, q4[d+3], c4);
            }
            float e0 = (jg > p0) ? 0.f : __expf(c0 * 0.125f);
            float e1 = (jg > p1) ? 0.f : __expf(c1 * 0.125f);
            float e2 = (jg > p2) ? 0.f : __expf(c2 * 0.125f);
            float e3 = (jg > p3) ? 0.f : __expf(c3 * 0.125f);
            float e4 = (jg > p4) ? 0.f : __expf(c4 * 0.125f);
            sP[ub + 0][j] = e0;
            sP[ub + 1][j] = e1;
            sP[ub + 2][j] = e2;
            sP[ub + 3][j] = e3;
            sP[ub + 4][j] = e4;
            // denominator partials (wave-reduce, accumulate in registers)
            #pragma unroll
            for (int off = 1; off < 64; off <<= 1) {
                e0 += __shfl_xor(e0, off);
                e1 += __shfl_xor(e1, off);
                e2 += __shfl_xor(e2, off);
                e3 += __shfl_xor(e3, off);
                e4 += __shfl_xor(e4, off);
            }
            den[0] += e0; den[1] += e1; den[2] += e2; den[3] += e3; den[4] += e4;
        }
        __syncthreads();   // sP visible; all reads of sK[cur] done

        // ---- write staged regs to the idle buffer (overlaps with PV) ----
        if (sub + 1 < KSUB) commit(cur ^ 1);

        // ---- PV accumulate (reads sP/sV[cur] only) ----
        #pragma unroll 4
        for (int j4 = 0; j4 < KC / 4; ++j4) {
            float4 pj0 = *(const float4*)&sP[tg][j4 * 4];
            float4 pj1 = (tg < 4) ? *(const float4*)&sP[16 + tg][j4 * 4]
                                  : (float4){0,0,0,0};
            float4 va = *(const float4*)&sV[cur][j4 * 4 + 0][d4p * 4];
            float4 vb = *(const float4*)&sV[cur][j4 * 4 + 1][d4p * 4];
            float4 vc = *(const float4*)&sV[cur][j4 * 4 + 2][d4p * 4];
            float4 vd = *(const float4*)&sV[cur][j4 * 4 + 3][d4p * 4];
            a0.x = fmaf(pj0.x, va.x, fmaf(pj0.y, vb.x, fmaf(pj0.z, vc.x, fmaf(pj0.w, vd.x, a0.x))));
            a0.y = fmaf(pj0.x, va.y, fmaf(pj0.y, vb.y, fmaf(pj0.z, vc.y, fmaf(pj0.w, vd.y, a0.y))));
            a0.z = fmaf(pj0.x, va.z, fmaf(pj0.y, vb.z, fmaf(pj0.z, vc.z, fmaf(pj0.w, vd.z, a0.z))));
            a0.w = fmaf(pj0.x, va.w, fmaf(pj0.y, vb.w, fmaf(pj0.z, vc.w, fmaf(pj0.w, vd.w, a0.w))));
            a1.x = fmaf(pj1.x, va.x, fmaf(pj1.y, vb.x, fmaf(pj1.z, vc.x, fmaf(pj1.w, vd.x, a1.x))));
            a1.y = fmaf(pj1.x, va.y, fmaf(pj1.y, vb.y, fmaf(pj1.z, vc.y, fmaf(pj1.w, vd.y, a1.y))));
            a1.z = fmaf(pj1.x, va.z, fmaf(pj1.y, vb.z, fmaf(pj1.z, vc.z, fmaf(pj1.w, vd.z, a1.z))));
            a1.w = fmaf(pj1.x, va.w, fmaf(pj1.y, vb.w, fmaf(pj1.z, vc.w, fmaf(pj1.w, vd.w, a1.w))));
        }
        __syncthreads();   // PV done with sP/sV[cur]; buf^1 writes visible
    }

    // ---- disjoint final writes ----
    if (lane == 0) {
        int base = (bh * NCH2 + ch) * UU + ug * 20 + ub;
        Lc[base + 0] = den[0]; Lc[base + 1] = den[1]; Lc[base + 2] = den[2];
        Lc[base + 3] = den[3]; Lc[base + 4] = den[4];
    }
    {
        int u0g = ug * 20 + tg;
        size_t o0 = ((size_t)(bh * NCH2 + ch) * UU + u0g) * DD + d4p * 4;
        *(float4*)(Oc + o0) = a0;
        if (tg < 4) {
            int u1g = ug * 20 + 16 + tg;
            size_t o1 = ((size_t)(bh * NCH2 + ch) * UU + u1g) * DD + d4p * 4;
            *(float4*)(Oc + o1) = a1;
        }
    }
}

// ---------------------------------------------------------------------------
// K4a: per-chunk sums of V along L (for cumsum), float4 lanes.
// ---------------------------------------------------------------------------
__global__ void k_chunksum(const float* __restrict__ V, float* __restrict__ chunkSum)
{
    int t  = threadIdx.x;
    int c  = blockIdx.x % CC;
    int bh = blockIdx.x / CC;
    int b  = bh / HH; int h = bh - b * HH;
    int d4 = t & 15, rs = t >> 4;

    float4 acc = {0,0,0,0};
    int l0 = c * LC;
    for (int l = l0 + rs; l < l0 + LC; l += 4) {
        float4 v = *(const float4*)(V + (((size_t)b * LL + l) * HH + h) * DD + d4 * 4);
        acc.x += v.x; acc.y += v.y; acc.z += v.z; acc.w += v.w;
    }
    acc.x += __shfl_xor(acc.x, 16); acc.y += __shfl_xor(acc.y, 16);
    acc.z += __shfl_xor(acc.z, 16); acc.w += __shfl_xor(acc.w, 16);
    acc.x += __shfl_xor(acc.x, 32); acc.y += __shfl_xor(acc.y, 32);
    acc.z += __shfl_xor(acc.z, 32); acc.w += __shfl_xor(acc.w, 32);
    if (t < 16)
        *(float4*)(chunkSum + ((size_t)bh * CC + c) * DD + d4 * 4) = acc;
}

// ---------------------------------------------------------------------------
// K4b: cumsum. One block per (bh, chunk) = 2048 blocks x 64 threads
// (8 waves/CU). Two-level scan: thread (d4, s) owns 8 rows; 8 independent
// float4 loads up front (MLP), register prefix, shfl-scan subtotals across
// the 4 subsegments, add chunk-prefix offset from chunkSum.
// ---------------------------------------------------------------------------
__global__ void k_cumsum(const float* __restrict__ V, const float* __restrict__ chunkSum,
                         float* __restrict__ out)
{
    int t  = threadIdx.x;                 // 64
    int c  = blockIdx.x & (CC - 1);
    int bh = blockIdx.x >> 6;
    int b  = bh / HH; int h = bh - b * HH;
    int d4 = t & 15, s = t >> 4;          // s: subsegment 0..3 (8 rows each)

    // chunk-prefix offset: s-groups split the c2 < c loop mod 4, then all-reduce
    const float4* CS4 = (const float4*)chunkSum;
    float4 off = {0,0,0,0};
    for (int c2 = s; c2 < c; c2 += 4) {
        float4 x = CS4[((size_t)bh * CC + c2) * 16 + d4];
        off.x += x.x; off.y += x.y; off.z += x.z; off.w += x.w;
    }
    off.x += __shfl_xor(off.x, 16); off.y += __shfl_xor(off.y, 16);
    off.z += __shfl_xor(off.z, 16); off.w += __shfl_xor(off.w, 16);
    off.x += __shfl_xor(off.x, 32); off.y += __shfl_xor(off.y, 32);
    off.z += __shfl_xor(off.z, 32); off.w += __shfl_xor(off.w, 32);

    int l0 = c * LC + s * 8;
    size_t base = (((size_t)b * LL + l0) * HH + h) * DD + d4 * 4;
    const size_t stride = (size_t)HH * DD;

    float4 v[8];
    #pragma unroll
    for (int r = 0; r < 8; ++r)
        v[r] = *(const float4*)(V + base + (size_t)r * stride);
    #pragma unroll
    for (int r = 1; r < 8; ++r) {
        v[r].x += v[r-1].x; v[r].y += v[r-1].y;
        v[r].z += v[r-1].z; v[r].w += v[r-1].w;
    }

    // inclusive Hillis-Steele scan of subtotals across s (lane = s*16 + d4)
    float4 inc = v[7];
    float4 p1;
    p1.x = __shfl_up(inc.x, 16); p1.y = __shfl_up(inc.y, 16);
    p1.z = __shfl_up(inc.z, 16); p1.w = __shfl_up(inc.w, 16);
    if (s >= 1) { inc.x += p1.x; inc.y += p1.y; inc.z += p1.z; inc.w += p1.w; }
    float4 p2;
    p2.x = __shfl_up(inc.x, 32); p2.y = __shfl_up(inc.y, 32);
    p2.z = __shfl_up(inc.z, 32); p2.w = __shfl_up(inc.w, 32);
    if (s >= 2) { inc.x += p2.x; inc.y += p2.y; inc.z += p2.z; inc.w += p2.w; }

    float4 add;
    add.x = off.x + inc.x - v[7].x;
    add.y = off.y + inc.y - v[7].y;
    add.z = off.z + inc.z - v[7].z;
    add.w = off.w + inc.w - v[7].w;

    #pragma unroll
    for (int r = 0; r < 8; ++r) {
        float4 o;
        o.x = v[r].x + add.x; o.y = v[r].y + add.y;
        o.z = v[r].z + add.z; o.w = v[r].w + add.w;
        *(float4*)(out + base + (size_t)r * stride) = o;
    }
}

// ---------------------------------------------------------------------------
// K5: finalize — out[pos] = (sum_ch Oc) / (sum_ch Lc). After k_cumsum.
// Grid = 32 bh, 256 threads (wave w covers u = w*10..+9, lane = d).
// ---------------------------------------------------------------------------
__global__ void k_finalize(const float* __restrict__ Oc, const float* __restrict__ Lc,
                           const int* __restrict__ topIdx, float* __restrict__ out)
{
    int bh = blockIdx.x;
    int b  = bh / HH, h = bh % HH;
    int t  = threadIdx.x;
    int d  = t & 63, w = t >> 6;
    for (int i = 0; i < 10; ++i) {
        int u = w * 10 + i;
        int pos = topIdx[bh * UU + u];
        float num = 0.f, den = 0.f;
        #pragma unroll
        for (int c = 0; c < NCH2; ++c) {
            num += Oc[((size_t)(bh * NCH2 + c) * UU + u) * DD + d];
            den += Lc[(bh * NCH2 + c) * UU + u];
        }
        out[(((size_t)b * LL + pos) * HH + h) * DD + d] = num / den;
    }
}

// ---------------------------------------------------------------------------
extern "C" void kernel_launch(void* const* d_in, const int* in_sizes, int n_in,
                              void* d_out, int out_size, void* d_ws, size_t ws_size,
                              hipStream_t stream)
{
    const float* Q   = (const float*)d_in[0];
    const float* K   = (const float*)d_in[1];
    const float* V   = (const float*)d_in[2];
    const int*   idx = (const int*)d_in[3];
    float* out = (float*)d_out;

    // ws layout (floats) — total ~864K floats ≈ 3.45 MB (R4-proven size)
    float* M        = (float*)d_ws;                               // 65536
    int*   topIdx   = (int*)(M + (size_t)BB * HH * LL);           // 1280
    float* Oc       = (float*)(topIdx + BB * HH * UU);            // 32*8*40*64 = 655360
    float* Lc       = Oc + (size_t)BB * HH * NCH2 * UU * DD;      // 32*8*40 = 10240
    float* chunkSum = Lc + BB * HH * NCH2 * UU;                   // 131072

    k_measure <<<BB * HH * LL / 4,     256, 0, stream>>>(Q, K, idx, M);
    k_topk    <<<BB * HH,               64, 0, stream>>>(M, topIdx);
    k_attn    <<<BB * HH * NCH2 * UG, 256, 0, stream>>>(Q, K, V, topIdx, Oc, Lc);
    k_chunksum<<<BB * HH * CC,          64, 0, stream>>>(V, chunkSum);
    k_cumsum  <<<BB * HH * CC,          64, 0, stream>>>(V, chunkSum, out);
    k_finalize<<<BB * HH,              256, 0, stream>>>(Oc, Lc, topIdx, out);
}

// Round 3
// 182.146 us; speedup vs baseline: 1.0756x; 1.0756x over previous
//
#include <hip/hip_runtime.h>
#include <hip/hip_bf16.h>
#include <math.h>

// fp32 I/O confirmed. index_sample is int32.
// R9: no mega-atomic fan-in (WRITE_SIZE blowup, XCD coherence serialization).
// R10: shift-free softmax => disjoint non-atomic partials. Oc/Lc + finalize.
// R11: k_attn T14 async-STAGE + LDS dbuf; k_cumsum 2-level scan. 196->194.
// R12: no-op — compiler had already folded kreg; kv[] array re-serialized.
// R13 POST-MORTEM (R11==R12 profile): k_attn WRITE 66MB = 512blk x 256thr x
// 128B x 4 cycles EXACTLY = lambda-captured pk[]/pv[] arrays in SCRATCH
// (SROA defeated by by-ref lambda closure; VGPR=88 of 256 proves regs
// unused). k_measure VGPR=32 = scheduler sank gathers serial (occupancy
// heuristic), latency-bound at 1.65TB/s.
// R13: (a) k_attn: de-lambda, 8 NAMED float4 staging regs via macros.
// (b) k_measure: named kv0..kv9 + amdgpu_waves_per_eu(4,8) (128-reg budget)
// + level-parallel shfl reduce (10 indep chains per level).

#define BB 4
#define LL 2048
#define HH 8
#define DD 64
#define SS 40
#define UU 40
#define CC 64
#define LC (LL/CC)    // 32 (cumsum chunking)

#define KC    64      // staged k-tile rows
#define NCH2  8       // k-chunks (256 rows each)
#define UG    2       // u-groups of 20
#define KSUB  4       // 64-row subtiles per chunk
#define KPAD  68      // K/V LDS row stride (floats)
#define PPAD  68

// ---------------------------------------------------------------------------
// K1: sparsity measure M[bh*L + i] = max_s(Q_i . K_idx[i,s]) - sum_s(...)/L
// one wave per query. lane = (sg = lane>>4, d4 = lane&15).
// R13: 10 named in-flight gathers, 128-VGPR budget, level-parallel reduce.
// ---------------------------------------------------------------------------
__attribute__((amdgpu_waves_per_eu(4, 8)))
__global__ void k_measure(const float* __restrict__ Q, const float* __restrict__ K,
                          const int* __restrict__ idx, float* __restrict__ M)
{
    int tid  = threadIdx.x;
    int lane = tid & 63;
    int wave = tid >> 6;
    int qid  = blockIdx.x * 4 + wave;          // qid = bh*L + i
    int bh = qid / LL;  int i = qid - bh * LL;
    int b  = bh / HH;   int h = bh - b * HH;

    int sg = lane >> 4;                        // sample group 0..3
    int d4 = lane & 15;                        // float4 slice of d

    const float* qrow = Q + (((size_t)b * LL + i) * HH + h) * DD;
    float4 qv = *(const float4*)(qrow + d4 * 4);

    const float* Kh = K + ((size_t)b * LL * HH + h) * DD;   // + kk*HH*DD
    const int* ip = idx + (size_t)i * SS;
    const size_t RS = (size_t)HH * DD;

    // all 10 index loads, then all 10 K-row gathers — named regs, MLP=10
    int kk0 = ip[0*4+sg], kk1 = ip[1*4+sg], kk2 = ip[2*4+sg], kk3 = ip[3*4+sg];
    int kk4 = ip[4*4+sg], kk5 = ip[5*4+sg], kk6 = ip[6*4+sg], kk7 = ip[7*4+sg];
    int kk8 = ip[8*4+sg], kk9 = ip[9*4+sg];
    float4 kv0 = *(const float4*)(Kh + (size_t)kk0 * RS + d4 * 4);
    float4 kv1 = *(const float4*)(Kh + (size_t)kk1 * RS + d4 * 4);
    float4 kv2 = *(const float4*)(Kh + (size_t)kk2 * RS + d4 * 4);
    float4 kv3 = *(const float4*)(Kh + (size_t)kk3 * RS + d4 * 4);
    float4 kv4 = *(const float4*)(Kh + (size_t)kk4 * RS + d4 * 4);
    float4 kv5 = *(const float4*)(Kh + (size_t)kk5 * RS + d4 * 4);
    float4 kv6 = *(const float4*)(Kh + (size_t)kk6 * RS + d4 * 4);
    float4 kv7 = *(const float4*)(Kh + (size_t)kk7 * RS + d4 * 4);
    float4 kv8 = *(const float4*)(Kh + (size_t)kk8 * RS + d4 * 4);
    float4 kv9 = *(const float4*)(Kh + (size_t)kk9 * RS + d4 * 4);

#define DOT4(kv) (fmaf(qv.w, kv.w, fmaf(qv.z, kv.z, fmaf(qv.y, kv.y, qv.x * kv.x))))
    float p0 = DOT4(kv0), p1 = DOT4(kv1), p2 = DOT4(kv2), p3 = DOT4(kv3);
    float p4 = DOT4(kv4), p5 = DOT4(kv5), p6 = DOT4(kv6), p7 = DOT4(kv7);
    float p8 = DOT4(kv8), p9 = DOT4(kv9);
#undef DOT4

    // level-parallel reduce across the 16-lane d4 group (10 indep chains)
#define RED(off) \
    p0 += __shfl_xor(p0, off); p1 += __shfl_xor(p1, off); \
    p2 += __shfl_xor(p2, off); p3 += __shfl_xor(p3, off); \
    p4 += __shfl_xor(p4, off); p5 += __shfl_xor(p5, off); \
    p6 += __shfl_xor(p6, off); p7 += __shfl_xor(p7, off); \
    p8 += __shfl_xor(p8, off); p9 += __shfl_xor(p9, off);
    RED(1) RED(2) RED(4) RED(8)
#undef RED

    float maxv = fmaxf(fmaxf(fmaxf(p0, p1), fmaxf(p2, p3)),
                       fmaxf(fmaxf(p4, p5), fmaxf(fmaxf(p6, p7), fmaxf(p8, p9))));
    float sumv = ((p0 + p1) + (p2 + p3)) + ((p4 + p5) + (p6 + p7)) + (p8 + p9);

    maxv = fmaxf(maxv, __shfl_xor(maxv, 16));
    sumv += __shfl_xor(sumv, 16);
    maxv = fmaxf(maxv, __shfl_xor(maxv, 32));
    sumv += __shfl_xor(sumv, 32);

    if (lane == 0) M[qid] = maxv - sumv * (1.0f / (float)LL);
}

// ---------------------------------------------------------------------------
// K2: top-40 per (b,h). One WAVE per bh, 2048 orderable keys in registers.
// Binary search for rank-40 threshold + idx tiebreak; zero LDS/barriers.
// ---------------------------------------------------------------------------
__global__ void k_topk(const float* __restrict__ M, int* __restrict__ topIdx)
{
    int lane = threadIdx.x;      // 64
    int bh   = blockIdx.x;
    const float* Mp = M + (size_t)bh * LL;

    unsigned k[32];
    #pragma unroll
    for (int r = 0; r < 32; ++r) {
        unsigned u = __float_as_uint(Mp[r * 64 + lane]);
        k[r] = (u & 0x80000000u) ? ~u : (u | 0x80000000u);  // order-preserving
    }

    unsigned T = 0u;
    for (int bit = 31; bit >= 0; --bit) {
        unsigned cand = T | (1u << bit);
        int c = 0;
        #pragma unroll
        for (int r = 0; r < 32; ++r) c += (k[r] >= cand) ? 1 : 0;
        #pragma unroll
        for (int off = 1; off < 64; off <<= 1) c += __shfl_xor(c, off);
        if (c >= UU) T = cand;
    }

    int cGT = 0, cGE = 0;
    #pragma unroll
    for (int r = 0; r < 32; ++r) {
        cGT += (k[r] > T) ? 1 : 0;
        cGE += (k[r] >= T) ? 1 : 0;
    }
    #pragma unroll
    for (int off = 1; off < 64; off <<= 1) {
        cGT += __shfl_xor(cGT, off);
        cGE += __shfl_xor(cGE, off);
    }

    int need = UU - cGT;
    int X = LL;
    if (cGE - cGT != need) {
        int lo2 = 0;
        for (int bit = 10; bit >= 0; --bit) {
            int cand = lo2 | (1 << bit);
            int c = 0;
            #pragma unroll
            for (int r = 0; r < 32; ++r)
                c += (k[r] == T && (r * 64 + lane) < cand) ? 1 : 0;
            #pragma unroll
            for (int off = 1; off < 64; off <<= 1) c += __shfl_xor(c, off);
            if (c < need) lo2 = cand;
        }
        X = lo2 + 1;
    }

    unsigned inMask = 0u;
    int cnt = 0;
    #pragma unroll
    for (int r = 0; r < 32; ++r) {
        bool in = (k[r] > T) || (k[r] == T && (r * 64 + lane) < X);
        if (in) { inMask |= 1u << r; ++cnt; }
    }
    int pre = cnt;
    #pragma unroll
    for (int off = 1; off < 64; off <<= 1) {
        int v = __shfl_up(pre, off);
        if (lane >= off) pre += v;
    }
    int slot = pre - cnt;
    #pragma unroll
    for (int r = 0; r < 32; ++r) {
        if ((inMask >> r) & 1u) {
            topIdx[bh * UU + slot] = r * 64 + lane;
            ++slot;
        }
    }
}

// ---------------------------------------------------------------------------
// K3: attention partials, shift-free softmax, NON-ATOMIC disjoint writes.
// Grid = bh(32) x ch(8) x ug(2) = 512 blocks, 256 threads, 2/CU resident.
// Double-buffered LDS + async-STAGE split (T14). R13: staging in 8 NAMED
// float4 registers (macros, no lambdas/arrays) — kills the scratch traffic
// that was 64MB of WRITE_SIZE.
// ---------------------------------------------------------------------------
__launch_bounds__(256, 2)
__global__ void k_attn(const float* __restrict__ Q, const float* __restrict__ K,
                       const float* __restrict__ V, const int* __restrict__ topIdx,
                       float* __restrict__ Oc, float* __restrict__ Lc)
{
    __shared__ float sK[2][KC][KPAD];
    __shared__ float sV[2][KC][KPAD];
    __shared__ float sP[20][PPAD];
    __shared__ int   sPos[UU];

    int t   = threadIdx.x;
    int bid = blockIdx.x;
    int bh  = bid / (NCH2 * UG);
    int rem = bid % (NCH2 * UG);
    int ch  = rem / UG, ug = rem % UG;
    int b   = bh / HH, h = bh % HH;

    if (t < UU) sPos[t] = topIdx[bh * UU + t];

    int j  = t & 63;                 // QK lane -> k-row within subtile
    int w  = t >> 6, lane = t & 63;  // wave mapping
    int ub = __builtin_amdgcn_readfirstlane(w) * 5;   // local u base (0,5,10,15)

    // PV accumulators: thread = (d4p = t&15, tg = t>>4); local u = tg, 16+tg
    int d4p = t & 15, tg = t >> 4;
    float4 a0 = {0,0,0,0}, a1 = {0,0,0,0};
    float den[5] = {0.f, 0.f, 0.f, 0.f, 0.f};

    const float* Kh = K + ((size_t)b * LL * HH + h) * DD;
    const float* Vh = V + ((size_t)b * LL * HH + h) * DD;

    // staged tile in 8 NAMED float4 regs; thread covers rows it*16+tg, slice d4p
    float4 pk0, pk1, pk2, pk3, pv0, pv1, pv2, pv3;

#define ISSUE(k0_) { \
    size_t g0 = (size_t)((k0_) +  0 + tg) * (HH * DD) + d4p * 4; \
    size_t g1 = (size_t)((k0_) + 16 + tg) * (HH * DD) + d4p * 4; \
    size_t g2 = (size_t)((k0_) + 32 + tg) * (HH * DD) + d4p * 4; \
    size_t g3 = (size_t)((k0_) + 48 + tg) * (HH * DD) + d4p * 4; \
    pk0 = *(const float4*)(Kh + g0); pv0 = *(const float4*)(Vh + g0); \
    pk1 = *(const float4*)(Kh + g1); pv1 = *(const float4*)(Vh + g1); \
    pk2 = *(const float4*)(Kh + g2); pv2 = *(const float4*)(Vh + g2); \
    pk3 = *(const float4*)(Kh + g3); pv3 = *(const float4*)(Vh + g3); \
}
#define COMMIT(buf_) { \
    *(float4*)&sK[buf_][ 0 + tg][d4p * 4] = pk0; *(float4*)&sV[buf_][ 0 + tg][d4p * 4] = pv0; \
    *(float4*)&sK[buf_][16 + tg][d4p * 4] = pk1; *(float4*)&sV[buf_][16 + tg][d4p * 4] = pv1; \
    *(float4*)&sK[buf_][32 + tg][d4p * 4] = pk2; *(float4*)&sV[buf_][32 + tg][d4p * 4] = pv2; \
    *(float4*)&sK[buf_][48 + tg][d4p * 4] = pk3; *(float4*)&sV[buf_][48 + tg][d4p * 4] = pv3; \
}

    int k0base = ch * KSUB * KC;
    ISSUE(k0base);
    COMMIT(0);
    __syncthreads();   // buf0 + sPos ready

    #pragma unroll
    for (int sub = 0; sub < KSUB; ++sub) {
        int cur = sub & 1;
        int k0  = k0base + sub * KC;

        if (sub + 1 < KSUB) ISSUE(k0 + KC);   // async: in flight across QK

        // ---- QK: lane owns k-row j; Q rows via scalar (wave-uniform) loads ----
        int jg = k0 + j;
        {
            int p0 = __builtin_amdgcn_readfirstlane(sPos[ug * 20 + ub + 0]);
            int p1 = __builtin_amdgcn_readfirstlane(sPos[ug * 20 + ub + 1]);
            int p2 = __builtin_amdgcn_readfirstlane(sPos[ug * 20 + ub + 2]);
            int p3 = __builtin_amdgcn_readfirstlane(sPos[ug * 20 + ub + 3]);
            int p4 = __builtin_amdgcn_readfirstlane(sPos[ug * 20 + ub + 4]);
            const float* q0 = Q + (((size_t)b * LL + p0) * HH + h) * DD;
            const float* q1 = Q + (((size_t)b * LL + p1) * HH + h) * DD;
            const float* q2 = Q + (((size_t)b * LL + p2) * HH + h) * DD;
            const float* q3 = Q + (((size_t)b * LL + p3) * HH + h) * DD;
            const float* q4 = Q + (((size_t)b * LL + p4) * HH + h) * DD;
            float c0 = 0.f, c1 = 0.f, c2 = 0.f, c3 = 0.f, c4 = 0.f;
            #pragma unroll
            for (int d4 = 0; d4 < 16; ++d4) {
                float4 kk = *(const float4*)&sK[cur][j][d4 * 4];
                int d = d4 * 4;
                c0 = fmaf(kk.x, q0[d], c0); c0 = fmaf(kk.y, q0[d+1], c0);
                c0 = fmaf(kk.z, q0[d+2], c0); c0 = fmaf(kk.w, q0[d+3], c0);
                c1 = fmaf(kk.x, q1[d], c1); c1 = fmaf(kk.y, q1[d+1], c1);
                c1 = fmaf(kk.z, q1[d+2], c1); c1 = fmaf(kk.w, q1[d+3], c1);
                c2 = fmaf(kk.x, q2[d], c2); c2 = fmaf(kk.y, q2[d+1], c2);
                c2 = fmaf(kk.z, q2[d+2], c2); c2 = fmaf(kk.w, q2[d+3], c2);
                c3 = fmaf(kk.x, q3[d], c3); c3 = fmaf(kk.y, q3[d+1], c3);
                c3 = fmaf(kk.z, q3[d+2], c3); c3 = fmaf(kk.w, q3[d+3], c3);
                c4 = fmaf(kk.x, q4[d], c4); c4 = fmaf(kk.y, q4[d+1], c4);
                c4 = fmaf(kk.z, q4[d+2], c4); c4 = fmaf(kk.w, q4[d+3], c4);
            }
            float e0 = (jg > p0) ? 0.f : __expf(c0 * 0.125f);
            float e1 = (jg > p1) ? 0.f : __expf(c1 * 0.125f);
            float e2 = (jg > p2) ? 0.f : __expf(c2 * 0.125f);
            float e3 = (jg > p3) ? 0.f : __expf(c3 * 0.125f);
            float e4 = (jg > p4) ? 0.f : __expf(c4 * 0.125f);
            sP[ub + 0][j] = e0;
            sP[ub + 1][j] = e1;
            sP[ub + 2][j] = e2;
            sP[ub + 3][j] = e3;
            sP[ub + 4][j] = e4;
            // denominator partials (wave-reduce, accumulate in registers)
            #pragma unroll
            for (int off = 1; off < 64; off <<= 1) {
                e0 += __shfl_xor(e0, off);
                e1 += __shfl_xor(e1, off);
                e2 += __shfl_xor(e2, off);
                e3 += __shfl_xor(e3, off);
                e4 += __shfl_xor(e4, off);
            }
            den[0] += e0; den[1] += e1; den[2] += e2; den[3] += e3; den[4] += e4;
        }
        __syncthreads();   // sP visible; all reads of sK[cur] done

        // ---- write staged regs to the idle buffer (overlaps with PV) ----
        if (sub + 1 < KSUB) {
            if (cur == 0) { COMMIT(1); } else { COMMIT(0); }
        }

        // ---- PV accumulate (reads sP/sV[cur] only) ----
        #pragma unroll 4
        for (int j4 = 0; j4 < KC / 4; ++j4) {
            float4 pj0 = *(const float4*)&sP[tg][j4 * 4];
            float4 pj1 = (tg < 4) ? *(const float4*)&sP[16 + tg][j4 * 4]
                                  : (float4){0,0,0,0};
            float4 va = *(const float4*)&sV[cur][j4 * 4 + 0][d4p * 4];
            float4 vb = *(const float4*)&sV[cur][j4 * 4 + 1][d4p * 4];
            float4 vc = *(const float4*)&sV[cur][j4 * 4 + 2][d4p * 4];
            float4 vd = *(const float4*)&sV[cur][j4 * 4 + 3][d4p * 4];
            a0.x = fmaf(pj0.x, va.x, fmaf(pj0.y, vb.x, fmaf(pj0.z, vc.x, fmaf(pj0.w, vd.x, a0.x))));
            a0.y = fmaf(pj0.x, va.y, fmaf(pj0.y, vb.y, fmaf(pj0.z, vc.y, fmaf(pj0.w, vd.y, a0.y))));
            a0.z = fmaf(pj0.x, va.z, fmaf(pj0.y, vb.z, fmaf(pj0.z, vc.z, fmaf(pj0.w, vd.z, a0.z))));
            a0.w = fmaf(pj0.x, va.w, fmaf(pj0.y, vb.w, fmaf(pj0.z, vc.w, fmaf(pj0.w, vd.w, a0.w))));
            a1.x = fmaf(pj1.x, va.x, fmaf(pj1.y, vb.x, fmaf(pj1.z, vc.x, fmaf(pj1.w, vd.x, a1.x))));
            a1.y = fmaf(pj1.x, va.y, fmaf(pj1.y, vb.y, fmaf(pj1.z, vc.y, fmaf(pj1.w, vd.y, a1.y))));
            a1.z = fmaf(pj1.x, va.z, fmaf(pj1.y, vb.z, fmaf(pj1.z, vc.z, fmaf(pj1.w, vd.z, a1.z))));
            a1.w = fmaf(pj1.x, va.w, fmaf(pj1.y, vb.w, fmaf(pj1.z, vc.w, fmaf(pj1.w, vd.w, a1.w))));
        }
        __syncthreads();   // PV done with sP/sV[cur]; buf^1 writes visible
    }
#undef ISSUE
#undef COMMIT

    // ---- disjoint final writes ----
    if (lane == 0) {
        int base = (bh * NCH2 + ch) * UU + ug * 20 + ub;
        Lc[base + 0] = den[0]; Lc[base + 1] = den[1]; Lc[base + 2] = den[2];
        Lc[base + 3] = den[3]; Lc[base + 4] = den[4];
    }
    {
        int u0g = ug * 20 + tg;
        size_t o0 = ((size_t)(bh * NCH2 + ch) * UU + u0g) * DD + d4p * 4;
        *(float4*)(Oc + o0) = a0;
        if (tg < 4) {
            int u1g = ug * 20 + 16 + tg;
            size_t o1 = ((size_t)(bh * NCH2 + ch) * UU + u1g) * DD + d4p * 4;
            *(float4*)(Oc + o1) = a1;
        }
    }
}

// ---------------------------------------------------------------------------
// K4a: per-chunk sums of V along L (for cumsum), float4 lanes.
// ---------------------------------------------------------------------------
__global__ void k_chunksum(const float* __restrict__ V, float* __restrict__ chunkSum)
{
    int t  = threadIdx.x;
    int c  = blockIdx.x % CC;
    int bh = blockIdx.x / CC;
    int b  = bh / HH; int h = bh - b * HH;
    int d4 = t & 15, rs = t >> 4;

    float4 acc = {0,0,0,0};
    int l0 = c * LC;
    for (int l = l0 + rs; l < l0 + LC; l += 4) {
        float4 v = *(const float4*)(V + (((size_t)b * LL + l) * HH + h) * DD + d4 * 4);
        acc.x += v.x; acc.y += v.y; acc.z += v.z; acc.w += v.w;
    }
    acc.x += __shfl_xor(acc.x, 16); acc.y += __shfl_xor(acc.y, 16);
    acc.z += __shfl_xor(acc.z, 16); acc.w += __shfl_xor(acc.w, 16);
    acc.x += __shfl_xor(acc.x, 32); acc.y += __shfl_xor(acc.y, 32);
    acc.z += __shfl_xor(acc.z, 32); acc.w += __shfl_xor(acc.w, 32);
    if (t < 16)
        *(float4*)(chunkSum + ((size_t)bh * CC + c) * DD + d4 * 4) = acc;
}

// ---------------------------------------------------------------------------
// K4b: cumsum. One block per (bh, chunk) = 2048 blocks x 64 threads
// (8 waves/CU). Two-level scan: thread (d4, s) owns 8 rows; 8 independent
// float4 loads up front (MLP), register prefix, shfl-scan subtotals across
// the 4 subsegments, add chunk-prefix offset from chunkSum.
// ---------------------------------------------------------------------------
__global__ void k_cumsum(const float* __restrict__ V, const float* __restrict__ chunkSum,
                         float* __restrict__ out)
{
    int t  = threadIdx.x;                 // 64
    int c  = blockIdx.x & (CC - 1);
    int bh = blockIdx.x >> 6;
    int b  = bh / HH; int h = bh - b * HH;
    int d4 = t & 15, s = t >> 4;          // s: subsegment 0..3 (8 rows each)

    // chunk-prefix offset: s-groups split the c2 < c loop mod 4, then all-reduce
    const float4* CS4 = (const float4*)chunkSum;
    float4 off = {0,0,0,0};
    for (int c2 = s; c2 < c; c2 += 4) {
        float4 x = CS4[((size_t)bh * CC + c2) * 16 + d4];
        off.x += x.x; off.y += x.y; off.z += x.z; off.w += x.w;
    }
    off.x += __shfl_xor(off.x, 16); off.y += __shfl_xor(off.y, 16);
    off.z += __shfl_xor(off.z, 16); off.w += __shfl_xor(off.w, 16);
    off.x += __shfl_xor(off.x, 32); off.y += __shfl_xor(off.y, 32);
    off.z += __shfl_xor(off.z, 32); off.w += __shfl_xor(off.w, 32);

    int l0 = c * LC + s * 8;
    size_t base = (((size_t)b * LL + l0) * HH + h) * DD + d4 * 4;
    const size_t stride = (size_t)HH * DD;

    float4 v[8];
    #pragma unroll
    for (int r = 0; r < 8; ++r)
        v[r] = *(const float4*)(V + base + (size_t)r * stride);
    #pragma unroll
    for (int r = 1; r < 8; ++r) {
        v[r].x += v[r-1].x; v[r].y += v[r-1].y;
        v[r].z += v[r-1].z; v[r].w += v[r-1].w;
    }

    // inclusive Hillis-Steele scan of subtotals across s (lane = s*16 + d4)
    float4 inc = v[7];
    float4 p1;
    p1.x = __shfl_up(inc.x, 16); p1.y = __shfl_up(inc.y, 16);
    p1.z = __shfl_up(inc.z, 16); p1.w = __shfl_up(inc.w, 16);
    if (s >= 1) { inc.x += p1.x; inc.y += p1.y; inc.z += p1.z; inc.w += p1.w; }
    float4 p2;
    p2.x = __shfl_up(inc.x, 32); p2.y = __shfl_up(inc.y, 32);
    p2.z = __shfl_up(inc.z, 32); p2.w = __shfl_up(inc.w, 32);
    if (s >= 2) { inc.x += p2.x; inc.y += p2.y; inc.z += p2.z; inc.w += p2.w; }

    float4 add;
    add.x = off.x + inc.x - v[7].x;
    add.y = off.y + inc.y - v[7].y;
    add.z = off.z + inc.z - v[7].z;
    add.w = off.w + inc.w - v[7].w;

    #pragma unroll
    for (int r = 0; r < 8; ++r) {
        float4 o;
        o.x = v[r].x + add.x; o.y = v[r].y + add.y;
        o.z = v[r].z + add.z; o.w = v[r].w + add.w;
        *(float4*)(out + base + (size_t)r * stride) = o;
    }
}

// ---------------------------------------------------------------------------
// K5: finalize — out[pos] = (sum_ch Oc) / (sum_ch Lc). After k_cumsum.
// Grid = 32 bh, 256 threads (wave w covers u = w*10..+9, lane = d).
// ---------------------------------------------------------------------------
__global__ void k_finalize(const float* __restrict__ Oc, const float* __restrict__ Lc,
                           const int* __restrict__ topIdx, float* __restrict__ out)
{
    int bh = blockIdx.x;
    int b  = bh / HH, h = bh % HH;
    int t  = threadIdx.x;
    int d  = t & 63, w = t >> 6;
    for (int i = 0; i < 10; ++i) {
        int u = w * 10 + i;
        int pos = topIdx[bh * UU + u];
        float num = 0.f, den = 0.f;
        #pragma unroll
        for (int c = 0; c < NCH2; ++c) {
            num += Oc[((size_t)(bh * NCH2 + c) * UU + u) * DD + d];
            den += Lc[(bh * NCH2 + c) * UU + u];
        }
        out[(((size_t)b * LL + pos) * HH + h) * DD + d] = num / den;
    }
}

// ---------------------------------------------------------------------------
extern "C" void kernel_launch(void* const* d_in, const int* in_sizes, int n_in,
                              void* d_out, int out_size, void* d_ws, size_t ws_size,
                              hipStream_t stream)
{
    const float* Q   = (const float*)d_in[0];
    const float* K   = (const float*)d_in[1];
    const float* V   = (const float*)d_in[2];
    const int*   idx = (const int*)d_in[3];
    float* out = (float*)d_out;

    // ws layout (floats) — total ~864K floats ≈ 3.45 MB (R4-proven size)
    float* M        = (float*)d_ws;                               // 65536
    int*   topIdx   = (int*)(M + (size_t)BB * HH * LL);           // 1280
    float* Oc       = (float*)(topIdx + BB * HH * UU);            // 32*8*40*64 = 655360
    float* Lc       = Oc + (size_t)BB * HH * NCH2 * UU * DD;      // 32*8*40 = 10240
    float* chunkSum = Lc + BB * HH * NCH2 * UU;                   // 131072

    k_measure <<<BB * HH * LL / 4,     256, 0, stream>>>(Q, K, idx, M);
    k_topk    <<<BB * HH,               64, 0, stream>>>(M, topIdx);
    k_attn    <<<BB * HH * NCH2 * UG, 256, 0, stream>>>(Q, K, V, topIdx, Oc, Lc);
    k_chunksum<<<BB * HH * CC,          64, 0, stream>>>(V, chunkSum);
    k_cumsum  <<<BB * HH * CC,          64, 0, stream>>>(V, chunkSum, out);
    k_finalize<<<BB * HH,              256, 0, stream>>>(Oc, Lc, topIdx, out);
}